// Round 1
// baseline (170.517 us; speedup 1.0000x reference)
//
#include <hip/hip_runtime.h>
#include <hip/hip_bf16.h>
#include <stdint.h>

typedef unsigned short u16;
typedef __bf16 bf16_t;
typedef bf16_t bf16x8 __attribute__((ext_vector_type(8)));
typedef float f32x4 __attribute__((ext_vector_type(4)));

#define MFMA16(a, b, c) __builtin_amdgcn_mfma_f32_16x16x32_bf16((a), (b), (c), 0, 0, 0)

#define NBATCH 8
#define SEQL 1024
#define EMB 1024
#define NHEAD 16
#define HD 64

static __device__ __forceinline__ u16 f2b(float f) {
  bf16_t b = (bf16_t)f;
  return __builtin_bit_cast(u16, b);
}

union V16 { uint4 u; bf16x8 b; };

static __device__ __forceinline__ bf16x8 ldb8(const u16* p) {
  V16 v; v.u = *(const uint4*)p; return v.b;
}

static __device__ __forceinline__ bf16x8 cvt8(const float* p) {
  float4 a = *(const float4*)p;
  float4 b = *(const float4*)(p + 4);
  bf16x8 r;
  r[0] = (bf16_t)a.x; r[1] = (bf16_t)a.y; r[2] = (bf16_t)a.z; r[3] = (bf16_t)a.w;
  r[4] = (bf16_t)b.x; r[5] = (bf16_t)b.y; r[6] = (bf16_t)b.z; r[7] = (bf16_t)b.w;
  return r;
}

// ---------------- Wo fp32 -> bf16 ----------------
__global__ __launch_bounds__(256) void k_wcvt(const float* __restrict__ Wo, u16* __restrict__ Wob) {
  int i = (blockIdx.x * 256 + threadIdx.x) * 4;
  float4 f = *(const float4*)(Wo + i);
  unsigned p0 = (unsigned)f2b(f.x) | ((unsigned)f2b(f.y) << 16);
  unsigned p1 = (unsigned)f2b(f.z) | ((unsigned)f2b(f.w) << 16);
  uint2 o; o.x = p0; o.y = p1;
  *(uint2*)(Wob + i) = o;
}

// ---------------- per-head projection ----------------
// Out[n,h,l,e] = sum_d X[n,l,h*64+d] * W[e,d]     (vmode=0)
// Out[n,h,e,l] = same, transposed                  (vmode=1, for V)
__global__ __launch_bounds__(256) void k_proj(const float* __restrict__ X, const float* __restrict__ W,
                                              u16* __restrict__ Out, int vmode) {
  __shared__ __align__(16) u16 sbuf[4608];
  int nh = blockIdx.x;
  int n = nh >> 4, h = nh & 15;
  int tid = threadIdx.x, w = tid >> 6, lane = tid & 63;
  int lr = lane & 15, lg = lane >> 4;

  // B-frags from W (shared by all row tiles): B[k=d][c=e] = W[e][d]
  bf16x8 bw[4][2];
#pragma unroll
  for (int c = 0; c < 4; ++c)
#pragma unroll
    for (int kk = 0; kk < 2; ++kk)
      bw[c][kk] = cvt8(W + (lr + 16 * c) * HD + kk * 32 + lg * 8);

#pragma unroll 1
  for (int it = 0; it < 4; ++it) {
    int rowblk = (blockIdx.y * 4 + it) * 4 + w;     // 0..63 (16-row tiles)
    int l = rowblk * 16 + lr;
    const float* xp = X + ((size_t)(n * SEQL + l)) * EMB + h * HD + lg * 8;
    bf16x8 a0 = cvt8(xp);        // d = 0..31
    bf16x8 a1 = cvt8(xp + 32);   // d = 32..63
    f32x4 acc[4];
#pragma unroll
    for (int c = 0; c < 4; ++c) {
      f32x4 z = {0.f, 0.f, 0.f, 0.f};
      z = MFMA16(a0, bw[c][0], z);
      z = MFMA16(a1, bw[c][1], z);
      acc[c] = z;
    }
    if (!vmode) {
      // restage per-wave 16x64 tile for coalesced global write
      u16* ob = sbuf + w * 1152;   // [16][72]
#pragma unroll
      for (int c = 0; c < 4; ++c)
#pragma unroll
        for (int rr = 0; rr < 4; ++rr)
          ob[(lg * 4 + rr) * 72 + lr + 16 * c] = f2b(acc[c][rr]);
      int orow = lane >> 2, oseg = lane & 3;
      uint4 v0 = *(const uint4*)(ob + orow * 72 + oseg * 16);
      uint4 v1 = *(const uint4*)(ob + orow * 72 + oseg * 16 + 8);
      u16* dst = Out + ((size_t)nh * SEQL + rowblk * 16 + orow) * HD + oseg * 16;
      *(uint4*)dst = v0;
      *(uint4*)(dst + 8) = v1;
    } else {
      // block-wide transpose: sbuf[d][lloc], 64x72
#pragma unroll
      for (int c = 0; c < 4; ++c)
#pragma unroll
        for (int rr = 0; rr < 4; ++rr)
          sbuf[(lr + 16 * c) * 72 + w * 16 + lg * 4 + rr] = f2b(acc[c][rr]);
      __syncthreads();
      int d = tid >> 2, seg = tid & 3;
      uint4 v0 = *(const uint4*)(sbuf + d * 72 + seg * 16);
      uint4 v1 = *(const uint4*)(sbuf + d * 72 + seg * 16 + 8);
      int lchunk = (blockIdx.y * 4 + it) * 64;
      u16* dst = Out + ((size_t)nh * HD + d) * SEQL + lchunk + seg * 16;
      *(uint4*)dst = v0;
      *(uint4*)(dst + 8) = v1;
      __syncthreads();
    }
  }
}

// ---------------- fused attention (per n,h and 64-row q-tile) ----------------
__global__ __launch_bounds__(256) void k_attn(const u16* __restrict__ Qp, const u16* __restrict__ Kp,
                                              const u16* __restrict__ Vt, const int* __restrict__ mask,
                                              u16* __restrict__ AO) {
  __shared__ __align__(16) u16 Ks[64 * 72];   // K-tile [kpos][d], +4 row pad
  __shared__ __align__(16) u16 Vs[64 * 72];   // V-tile transposed [d][kpos], +4 row pad
  __shared__ __align__(16) u16 Ps[4 * 1152];  // per-wave P [16][72]
  int nh = blockIdx.x, qt = blockIdx.y;
  int n = nh >> 4, h = nh & 15;
  int tid = threadIdx.x, w = tid >> 6, lane = tid & 63;
  int lr = lane & 15, lg = lane >> 4;
  int q0 = qt * 64 + w * 16;

  // Q A-frags held in registers for whole kernel
  const u16* qb = Qp + ((size_t)nh * SEQL + q0 + lr) * HD + lg * 8;
  bf16x8 aq0 = ldb8(qb), aq1 = ldb8(qb + 32);

  f32x4 O[4];
#pragma unroll
  for (int c = 0; c < 4; ++c) { f32x4 z = {0.f, 0.f, 0.f, 0.f}; O[c] = z; }
  float lsum[4] = {0.f, 0.f, 0.f, 0.f};
  u16* pb = Ps + w * 1152;
  int sr = tid >> 2, sseg = tid & 3;
  const float SC = 0.03125f;  // 1/sqrt(EMBED)

#pragma unroll 1
  for (int kt = 0; kt < 16; ++kt) {
    {  // cooperative staging of K and V tiles
      const u16* s = Kp + ((size_t)nh * SEQL + kt * 64 + sr) * HD + sseg * 16;
      *(uint4*)(Ks + sr * 72 + sseg * 16)     = *(const uint4*)s;
      *(uint4*)(Ks + sr * 72 + sseg * 16 + 8) = *(const uint4*)(s + 8);
      const u16* v = Vt + ((size_t)nh * HD + sr) * SEQL + kt * 64 + sseg * 16;
      *(uint4*)(Vs + sr * 72 + sseg * 16)     = *(const uint4*)v;
      *(uint4*)(Vs + sr * 72 + sseg * 16 + 8) = *(const uint4*)(v + 8);
    }
    __syncthreads();
    // S = Q K^T  (16 x 64), then exp (no max-sub: logits bounded ~|2|)
#pragma unroll
    for (int c = 0; c < 4; ++c) {
      const u16* kp = Ks + (lr + 16 * c) * 72 + lg * 8;
      f32x4 s = {0.f, 0.f, 0.f, 0.f};
      s = MFMA16(aq0, ldb8(kp), s);
      s = MFMA16(aq1, ldb8(kp + 32), s);
      int mk = mask[n * SEQL + kt * 64 + 16 * c + lr];
#pragma unroll
      for (int rr = 0; rr < 4; ++rr) {
        float e = (mk != 0 ? s[rr] : -1e10f) * SC;
        float p = __expf(e);
        lsum[rr] += p;
        pb[(lg * 4 + rr) * 72 + lr + 16 * c] = f2b(p);
      }
    }
    // O += P V
    bf16x8 pa0 = ldb8(pb + lr * 72 + lg * 8);
    bf16x8 pa1 = ldb8(pb + lr * 72 + lg * 8 + 32);
#pragma unroll
    for (int c = 0; c < 4; ++c) {
      const u16* vp = Vs + (lr + 16 * c) * 72 + lg * 8;
      O[c] = MFMA16(pa0, ldb8(vp), O[c]);
      O[c] = MFMA16(pa1, ldb8(vp + 32), O[c]);
    }
    __syncthreads();
  }
  // row sums: reduce across the 16 lanes sharing a row-group
  float inv[4];
#pragma unroll
  for (int rr = 0; rr < 4; ++rr) {
    float t = lsum[rr];
    t += __shfl_xor(t, 1);
    t += __shfl_xor(t, 2);
    t += __shfl_xor(t, 4);
    t += __shfl_xor(t, 8);
    inv[rr] = 1.f / t;
  }
  // normalize + restage + coalesced write AO[n][q][h*64+d]
#pragma unroll
  for (int c = 0; c < 4; ++c)
#pragma unroll
    for (int rr = 0; rr < 4; ++rr)
      pb[(lg * 4 + rr) * 72 + lr + 16 * c] = f2b(O[c][rr] * inv[rr]);
  int orow = lane >> 2, oseg = lane & 3;
  uint4 v0 = *(const uint4*)(pb + orow * 72 + oseg * 16);
  uint4 v1 = *(const uint4*)(pb + orow * 72 + oseg * 16 + 8);
  u16* dst = AO + ((size_t)(n * SEQL + q0 + orow)) * EMB + h * HD + oseg * 16;
  *(uint4*)dst = v0;
  *(uint4*)(dst + 8) = v1;
}

// ---------------- output projection: Y = AO (8192x1024) * Wo^T + bo ----------------
__global__ __launch_bounds__(256) void k_out(const u16* __restrict__ AO, const u16* __restrict__ Wob,
                                             const float* __restrict__ bo, float* __restrict__ Y) {
  __shared__ __align__(16) u16 As[128 * 32];
  __shared__ __align__(16) u16 Bs[128 * 32];
  int n0 = blockIdx.x * 128, m0 = blockIdx.y * 128;
  int tid = threadIdx.x, w = tid >> 6, lane = tid & 63;
  int lr = lane & 15, lg = lane >> 4;
  int wr = w >> 1, wc = w & 1;
  f32x4 acc[4][4] = {};
  int sr = tid >> 1, sc = (tid & 1) * 16;
#pragma unroll 1
  for (int kb = 0; kb < 32; ++kb) {
    const u16* as = AO + (size_t)(m0 + sr) * EMB + kb * 32 + sc;
    *(uint4*)(As + sr * 32 + sc)     = *(const uint4*)as;
    *(uint4*)(As + sr * 32 + sc + 8) = *(const uint4*)(as + 8);
    const u16* bs = Wob + (size_t)(n0 + sr) * EMB + kb * 32 + sc;
    *(uint4*)(Bs + sr * 32 + sc)     = *(const uint4*)bs;
    *(uint4*)(Bs + sr * 32 + sc + 8) = *(const uint4*)(bs + 8);
    __syncthreads();
    bf16x8 a[4], b[4];
#pragma unroll
    for (int mi = 0; mi < 4; ++mi)
      a[mi] = ldb8(As + (wr * 64 + mi * 16 + lr) * 32 + lg * 8);
#pragma unroll
    for (int ni = 0; ni < 4; ++ni)
      b[ni] = ldb8(Bs + (wc * 64 + ni * 16 + lr) * 32 + lg * 8);
#pragma unroll
    for (int mi = 0; mi < 4; ++mi)
#pragma unroll
      for (int ni = 0; ni < 4; ++ni)
        acc[mi][ni] = MFMA16(a[mi], b[ni], acc[mi][ni]);
    __syncthreads();
  }
#pragma unroll
  for (int ni = 0; ni < 4; ++ni) {
    float bov = bo[n0 + wc * 64 + ni * 16 + lr];
#pragma unroll
    for (int mi = 0; mi < 4; ++mi) {
#pragma unroll
      for (int rr = 0; rr < 4; ++rr) {
        int row = m0 + wr * 64 + mi * 16 + lg * 4 + rr;
        int col = n0 + wc * 64 + ni * 16 + lr;
        Y[(size_t)row * EMB + col] = acc[mi][ni][rr] + bov;
      }
    }
  }
}

extern "C" void kernel_launch(void* const* d_in, const int* in_sizes, int n_in,
                              void* d_out, int out_size, void* d_ws, size_t ws_size,
                              hipStream_t stream) {
  (void)in_sizes; (void)n_in; (void)out_size; (void)ws_size;
  const float* values = (const float*)d_in[0];
  const float* keys   = (const float*)d_in[1];
  const float* query  = (const float*)d_in[2];
  const int*   mask   = (const int*)d_in[3];
  const float* Wv = (const float*)d_in[4];
  const float* Wk = (const float*)d_in[5];
  const float* Wq = (const float*)d_in[6];
  const float* Wo = (const float*)d_in[7];
  const float* bo = (const float*)d_in[8];
  float* out = (float*)d_out;

  // workspace layout (u16 units): Qp 8M | Kp 8M | Vt 8M | AO 8M | Wob 1M  => 66 MB
  u16* ws  = (u16*)d_ws;
  u16* Qp  = ws;
  u16* Kp  = ws + (size_t)8 * 1024 * 1024;
  u16* Vt  = ws + (size_t)16 * 1024 * 1024;
  u16* AO  = ws + (size_t)24 * 1024 * 1024;
  u16* Wob = ws + (size_t)32 * 1024 * 1024;

  k_wcvt<<<dim3(1024), dim3(256), 0, stream>>>(Wo, Wob);
  k_proj<<<dim3(128, 4), dim3(256), 0, stream>>>(values, Wv, Vt, 1);
  k_proj<<<dim3(128, 4), dim3(256), 0, stream>>>(keys, Wk, Kp, 0);
  k_proj<<<dim3(128, 4), dim3(256), 0, stream>>>(query, Wq, Qp, 0);
  k_attn<<<dim3(128, 16), dim3(256), 0, stream>>>(Qp, Kp, Vt, mask, AO);
  k_out<<<dim3(8, 64), dim3(256), 0, stream>>>(AO, Wob, bo, out);
}

// Round 3
// 130.617 us; speedup vs baseline: 1.3055x; 1.3055x over previous
//
#include <hip/hip_runtime.h>
#include <hip/hip_bf16.h>
#include <stdint.h>

typedef unsigned short u16;
typedef __bf16 bf16_t;
typedef bf16_t bf16x8 __attribute__((ext_vector_type(8)));
typedef float f32x4 __attribute__((ext_vector_type(4)));
typedef float f32x16 __attribute__((ext_vector_type(16)));

#define MFMA16(a, b, c) __builtin_amdgcn_mfma_f32_16x16x32_bf16((a), (b), (c), 0, 0, 0)
#define MFMA32(a, b, c) __builtin_amdgcn_mfma_f32_32x32x16_bf16((a), (b), (c), 0, 0, 0)

#define NBATCH 8
#define SEQL 1024
#define EMB 1024
#define NHEAD 16
#define HD 64

static __device__ __forceinline__ u16 f2b(float f) {
  bf16_t b = (bf16_t)f;
  return __builtin_bit_cast(u16, b);
}

union V16 { uint4 u; bf16x8 b; };

static __device__ __forceinline__ bf16x8 ldb8(const u16* p) {
  V16 v; v.u = *(const uint4*)p; return v.b;
}

static __device__ __forceinline__ bf16x8 cvt8(const float* p) {
  float4 a = *(const float4*)p;
  float4 b = *(const float4*)(p + 4);
  bf16x8 r;
  r[0] = (bf16_t)a.x; r[1] = (bf16_t)a.y; r[2] = (bf16_t)a.z; r[3] = (bf16_t)a.w;
  r[4] = (bf16_t)b.x; r[5] = (bf16_t)b.y; r[6] = (bf16_t)b.z; r[7] = (bf16_t)b.w;
  return r;
}

// async global -> LDS, 16B per lane; lds ptr must be wave-uniform (HW adds lane*16)
static __device__ __forceinline__ void gload16(const void* g, void* l) {
  __builtin_amdgcn_global_load_lds((__attribute__((address_space(1))) void*)(uintptr_t)g,
                                   (__attribute__((address_space(3))) void*)l, 16, 0, 0);
}

static __device__ __forceinline__ unsigned cvtpk(float lo, float hi) {
  unsigned r;
  asm("v_cvt_pk_bf16_f32 %0, %1, %2" : "=v"(r) : "v"(lo), "v"(hi));
  return r;
}

static __device__ __forceinline__ f32x16 zero16() {
  f32x16 z;
#pragma unroll
  for (int i = 0; i < 16; ++i) z[i] = 0.f;
  return z;
}

// ---------------- Wo fp32 -> bf16 ----------------
__global__ __launch_bounds__(256) void k_wcvt(const float* __restrict__ Wo, u16* __restrict__ Wob) {
  int i = (blockIdx.x * 256 + threadIdx.x) * 4;
  float4 f = *(const float4*)(Wo + i);
  unsigned p0 = (unsigned)f2b(f.x) | ((unsigned)f2b(f.y) << 16);
  unsigned p1 = (unsigned)f2b(f.z) | ((unsigned)f2b(f.w) << 16);
  uint2 o; o.x = p0; o.y = p1;
  *(uint2*)(Wob + i) = o;
}

// ---------------- per-head projection (unchanged from R0) ----------------
__global__ __launch_bounds__(256) void k_proj(const float* __restrict__ X, const float* __restrict__ W,
                                              u16* __restrict__ Out, int vmode) {
  __shared__ __align__(16) u16 sbuf[4608];
  int nh = blockIdx.x;
  int n = nh >> 4, h = nh & 15;
  int tid = threadIdx.x, w = tid >> 6, lane = tid & 63;
  int lr = lane & 15, lg = lane >> 4;

  bf16x8 bw[4][2];
#pragma unroll
  for (int c = 0; c < 4; ++c)
#pragma unroll
    for (int kk = 0; kk < 2; ++kk)
      bw[c][kk] = cvt8(W + (lr + 16 * c) * HD + kk * 32 + lg * 8);

#pragma unroll 1
  for (int it = 0; it < 4; ++it) {
    int rowblk = (blockIdx.y * 4 + it) * 4 + w;
    int l = rowblk * 16 + lr;
    const float* xp = X + ((size_t)(n * SEQL + l)) * EMB + h * HD + lg * 8;
    bf16x8 a0 = cvt8(xp);
    bf16x8 a1 = cvt8(xp + 32);
    f32x4 acc[4];
#pragma unroll
    for (int c = 0; c < 4; ++c) {
      f32x4 z = {0.f, 0.f, 0.f, 0.f};
      z = MFMA16(a0, bw[c][0], z);
      z = MFMA16(a1, bw[c][1], z);
      acc[c] = z;
    }
    if (!vmode) {
      u16* ob = sbuf + w * 1152;
#pragma unroll
      for (int c = 0; c < 4; ++c)
#pragma unroll
        for (int rr = 0; rr < 4; ++rr)
          ob[(lg * 4 + rr) * 72 + lr + 16 * c] = f2b(acc[c][rr]);
      int orow = lane >> 2, oseg = lane & 3;
      uint4 v0 = *(const uint4*)(ob + orow * 72 + oseg * 16);
      uint4 v1 = *(const uint4*)(ob + orow * 72 + oseg * 16 + 8);
      u16* dst = Out + ((size_t)nh * SEQL + rowblk * 16 + orow) * HD + oseg * 16;
      *(uint4*)dst = v0;
      *(uint4*)(dst + 8) = v1;
    } else {
#pragma unroll
      for (int c = 0; c < 4; ++c)
#pragma unroll
        for (int rr = 0; rr < 4; ++rr)
          sbuf[(lr + 16 * c) * 72 + w * 16 + lg * 4 + rr] = f2b(acc[c][rr]);
      __syncthreads();
      int d = tid >> 2, seg = tid & 3;
      uint4 v0 = *(const uint4*)(sbuf + d * 72 + seg * 16);
      uint4 v1 = *(const uint4*)(sbuf + d * 72 + seg * 16 + 8);
      int lchunk = (blockIdx.y * 4 + it) * 64;
      u16* dst = Out + ((size_t)nh * HD + d) * SEQL + lchunk + seg * 16;
      *(uint4*)dst = v0;
      *(uint4*)(dst + 8) = v1;
      __syncthreads();
    }
  }
}

// ---------------- fused attention, swapped-QK^T 32x32 structure ----------------
// block = 4 waves, 128 q rows (32/wave); KV tiles of 64, double-buffered.
// K LDS tile: [kpos][d] rows of 128B, XOR-swizzled (slot ^= row&7).
// V LDS tile: [d][kpos] rows of 128B, same swizzle.
__global__ __launch_bounds__(256) void k_attn2(const u16* __restrict__ Qp, const u16* __restrict__ Kp,
                                               const u16* __restrict__ Vt, const int* __restrict__ mask,
                                               u16* __restrict__ AO) {
  __shared__ __align__(16) u16 SMEM[2][8192];   // [buf][ K:0..4095 | V:4096..8191 ]
  __shared__ unsigned long long mkb[16];
  __shared__ __align__(16) float winv[4][32];

  int nh = blockIdx.x;
  int n = nh >> 4, h = nh & 15;
  int tid = threadIdx.x, w = tid >> 6, lane = tid & 63;
  int q = lane & 31, hi = lane >> 5;
  int q0w = blockIdx.y * 128 + w * 32;

  // Q B-frags in registers for the whole kernel: B[k=d][n=q], d = 16*kk + 8*hi + j
  const u16* qbase = Qp + ((size_t)nh * SEQL + q0w + q) * HD + hi * 8;
  bf16x8 bq[4];
#pragma unroll
  for (int kk = 0; kk < 4; ++kk) bq[kk] = ldb8(qbase + kk * 16);

  const u16* gK = Kp + (size_t)nh * SEQL * HD;
  const u16* gV = Vt + (size_t)nh * HD * SEQL;
  int sr = lane >> 3, sslot = lane & 7;

  auto STAGE = [&](int b, int t) {
#pragma unroll
    for (int j = 0; j < 2; ++j) {
      int r = 16 * w + 8 * j + sr;              // tile row 0..63
      int slot = sslot ^ (r & 7);               // pre-swizzled source chunk
      gload16(gK + ((size_t)(t * 64 + r)) * HD + slot * 8,
              &SMEM[b][w * 1024 + j * 512]);
      gload16(gV + (size_t)r * SEQL + t * 64 + slot * 8,
              &SMEM[b][4096 + w * 1024 + j * 512]);
    }
  };

  STAGE(0, 0);
  // per-tile mask bitmasks via ballot (input mask is all-ones -> fast path)
#pragma unroll 1
  for (int t = w; t < 16; t += 4) {
    int mv = mask[n * SEQL + t * 64 + lane];
    unsigned long long b = __ballot(mv != 0);
    if (lane == 0) mkb[t] = b;
  }
  __syncthreads();

  f32x16 oacc[2];
  oacc[0] = zero16(); oacc[1] = zero16();
  float lsum = 0.f;
  const float C2 = 0.045084222f;   // (1/sqrt(EMB)) * log2(e)
  int buf = 0;

#pragma unroll 1
  for (int kt = 0; kt < 16; ++kt) {
    if (kt < 15) STAGE(buf ^ 1, kt + 1);
    const u16* KB = &SMEM[buf][0];
    const u16* VB = &SMEM[buf][4096];
    unsigned long long mb = mkb[kt];

    // S^T = K Q^T : lane holds S[kpos=32c+4hi+(rr&3)+8(rr>>2)][q]
    f32x16 sacc[2];
#pragma unroll
    for (int c = 0; c < 2; ++c) {
      f32x16 s = zero16();
      int row = 32 * c + q;
      int swz = (row & 7) << 3;
      const u16* kr = KB + row * 64;
#pragma unroll
      for (int kk = 0; kk < 4; ++kk) {
        bf16x8 ak = ldb8(kr + ((16 * kk + 8 * hi) ^ swz));
        s = MFMA32(ak, bq[kk], s);
      }
      sacc[c] = s;
    }

    // exp (logits bounded, no max-sub) + optional mask + local denominator
#pragma unroll
    for (int c = 0; c < 2; ++c)
#pragma unroll
      for (int rr = 0; rr < 16; ++rr)
        sacc[c][rr] = __builtin_amdgcn_exp2f(sacc[c][rr] * C2);
    if (mb != ~0ull) {
#pragma unroll
      for (int c = 0; c < 2; ++c)
#pragma unroll
        for (int rr = 0; rr < 16; ++rr) {
          int kpos = 32 * c + 4 * hi + (rr & 3) + 8 * (rr >> 2);
          if (!((mb >> kpos) & 1)) sacc[c][rr] = 0.f;
        }
    }
#pragma unroll
    for (int c = 0; c < 2; ++c)
#pragma unroll
      for (int rr = 0; rr < 16; ++rr) lsum += sacc[c][rr];

    // pack to bf16 pair-words: wpk[c][w2][u] = (p[4w2+2u], p[4w2+2u+1])
    unsigned wpk[2][4][2];
#pragma unroll
    for (int c = 0; c < 2; ++c)
#pragma unroll
      for (int w2 = 0; w2 < 4; ++w2) {
        wpk[c][w2][0] = cvtpk(sacc[c][4 * w2 + 0], sacc[c][4 * w2 + 1]);
        wpk[c][w2][1] = cvtpk(sacc[c][4 * w2 + 2], sacc[c][4 * w2 + 3]);
      }

    // redistribute to PV A-frags via permlane32_swap:
    // pa[t] (t=2c+p2) needs kpos = 16t + 8hi + j; quadA from even w2, quadB from odd w2.
    bf16x8 pa[4];
#pragma unroll
    for (int t = 0; t < 4; ++t) {
      int c = t >> 1, p2 = t & 1;
      auto r0 = __builtin_amdgcn_permlane32_swap(wpk[c][2 * p2][0], wpk[c][2 * p2 + 1][0], false, false);
      auto r1 = __builtin_amdgcn_permlane32_swap(wpk[c][2 * p2][1], wpk[c][2 * p2 + 1][1], false, false);
      union { unsigned u[4]; bf16x8 v; } pu;
      pu.u[0] = r0[0]; pu.u[1] = r1[0]; pu.u[2] = r0[1]; pu.u[3] = r1[1];
      pa[t] = pu.v;
    }

    // O += P V : B[k=kpos][n=d] from V^T tile rows (d), same swizzle
#pragma unroll
    for (int cp = 0; cp < 2; ++cp) {
      int row = 32 * cp + q;
      int swz = (row & 7) << 3;
      const u16* vr = VB + row * 64;
      f32x16 o = oacc[cp];
#pragma unroll
      for (int t = 0; t < 4; ++t) {
        bf16x8 vb = ldb8(vr + ((16 * t + 8 * hi) ^ swz));
        o = MFMA32(pa[t], vb, o);
      }
      oacc[cp] = o;
    }
    __syncthreads();
    buf ^= 1;
  }

  // softmax denominators: q-row split across lane pair (q, q+32)
  float tot = lsum + __shfl_xor(lsum, 32);
  float inv = 1.0f / tot;
  if (!hi) winv[w][q] = inv;           // wave-local; compiler orders LDS RAW
  float iq[16];
#pragma unroll
  for (int w2 = 0; w2 < 4; ++w2) {
    float4 f = *(const float4*)&winv[w][8 * w2 + 4 * hi];
    iq[4 * w2 + 0] = f.x; iq[4 * w2 + 1] = f.y; iq[4 * w2 + 2] = f.z; iq[4 * w2 + 3] = f.w;
  }

  // normalize + restage per-wave [32][80] + coalesced AO write
  u16* ob = &SMEM[0][0] + w * 2560;
#pragma unroll
  for (int cp = 0; cp < 2; ++cp)
#pragma unroll
    for (int rr = 0; rr < 16; ++rr) {
      int qr = (rr & 3) + 8 * (rr >> 2) + 4 * hi;
      ob[qr * 80 + 32 * cp + q] = f2b(oacc[cp][rr] * iq[rr]);
    }
  // each lane writes a FULL 32-u16 half-row (fix: R1 only wrote 16 of 32)
  int orow = lane >> 1, ohalf = lane & 1;
  const u16* srcp = ob + orow * 80 + ohalf * 32;
  uint4 v0 = *(const uint4*)srcp;
  uint4 v1 = *(const uint4*)(srcp + 8);
  uint4 v2 = *(const uint4*)(srcp + 16);
  uint4 v3 = *(const uint4*)(srcp + 24);
  u16* dst = AO + ((size_t)(n * SEQL + q0w + orow)) * EMB + h * HD + ohalf * 32;
  *(uint4*)dst = v0;
  *(uint4*)(dst + 8) = v1;
  *(uint4*)(dst + 16) = v2;
  *(uint4*)(dst + 24) = v3;
}

// ---------------- output projection: Y = AO (8192x1024) * Wo^T + bo ----------------
// m97-style: global_load_lds staging, double-buffered, 1 barrier per K-step.
__global__ __launch_bounds__(256) void k_out(const u16* __restrict__ AO, const u16* __restrict__ Wob,
                                             const float* __restrict__ bo, float* __restrict__ Y) {
  __shared__ __align__(16) u16 As[2][4096];
  __shared__ __align__(16) u16 Bs[2][4096];
  int n0 = blockIdx.x * 128, m0 = blockIdx.y * 128;
  int tid = threadIdx.x, w = tid >> 6, lane = tid & 63;
  int lr = lane & 15, lg = lane >> 4;
  int wr = w >> 1, wc = w & 1;
  int srow = lane >> 2, sseg = lane & 3;

  auto STAGE = [&](int b, int kb) {
#pragma unroll
    for (int j = 0; j < 2; ++j) {
      int row = 32 * w + 16 * j + srow;
      gload16(AO + (size_t)(m0 + row) * EMB + kb * 32 + sseg * 8, &As[b][w * 1024 + j * 512]);
      gload16(Wob + (size_t)(n0 + row) * EMB + kb * 32 + sseg * 8, &Bs[b][w * 1024 + j * 512]);
    }
  };

  f32x4 acc[4][4] = {};
  STAGE(0, 0);
  __syncthreads();
  int buf = 0;
#pragma unroll 1
  for (int kb = 0; kb < 32; ++kb) {
    if (kb < 31) STAGE(buf ^ 1, kb + 1);
    bf16x8 a[4], b[4];
#pragma unroll
    for (int mi = 0; mi < 4; ++mi)
      a[mi] = ldb8(&As[buf][(wr * 64 + mi * 16 + lr) * 32 + lg * 8]);
#pragma unroll
    for (int ni = 0; ni < 4; ++ni)
      b[ni] = ldb8(&Bs[buf][(wc * 64 + ni * 16 + lr) * 32 + lg * 8]);
#pragma unroll
    for (int mi = 0; mi < 4; ++mi)
#pragma unroll
      for (int ni = 0; ni < 4; ++ni)
        acc[mi][ni] = MFMA16(a[mi], b[ni], acc[mi][ni]);
    __syncthreads();
    buf ^= 1;
  }
#pragma unroll
  for (int ni = 0; ni < 4; ++ni) {
    float bov = bo[n0 + wc * 64 + ni * 16 + lr];
#pragma unroll
    for (int mi = 0; mi < 4; ++mi) {
#pragma unroll
      for (int rr = 0; rr < 4; ++rr) {
        int row = m0 + wr * 64 + mi * 16 + lg * 4 + rr;
        int col = n0 + wc * 64 + ni * 16 + lr;
        Y[(size_t)row * EMB + col] = acc[mi][ni][rr] + bov;
      }
    }
  }
}

extern "C" void kernel_launch(void* const* d_in, const int* in_sizes, int n_in,
                              void* d_out, int out_size, void* d_ws, size_t ws_size,
                              hipStream_t stream) {
  (void)in_sizes; (void)n_in; (void)out_size; (void)ws_size;
  const float* values = (const float*)d_in[0];
  const float* keys   = (const float*)d_in[1];
  const float* query  = (const float*)d_in[2];
  const int*   mask   = (const int*)d_in[3];
  const float* Wv = (const float*)d_in[4];
  const float* Wk = (const float*)d_in[5];
  const float* Wq = (const float*)d_in[6];
  const float* Wo = (const float*)d_in[7];
  const float* bo = (const float*)d_in[8];
  float* out = (float*)d_out;

  u16* ws  = (u16*)d_ws;
  u16* Qp  = ws;
  u16* Kp  = ws + (size_t)8 * 1024 * 1024;
  u16* Vt  = ws + (size_t)16 * 1024 * 1024;
  u16* AO  = ws + (size_t)24 * 1024 * 1024;
  u16* Wob = ws + (size_t)32 * 1024 * 1024;

  k_wcvt<<<dim3(1024), dim3(256), 0, stream>>>(Wo, Wob);
  k_proj<<<dim3(128, 4), dim3(256), 0, stream>>>(values, Wv, Vt, 1);
  k_proj<<<dim3(128, 4), dim3(256), 0, stream>>>(keys, Wk, Kp, 0);
  k_proj<<<dim3(128, 4), dim3(256), 0, stream>>>(query, Wq, Qp, 0);
  k_attn2<<<dim3(128, 8), dim3(256), 0, stream>>>(Qp, Kp, Vt, mask, AO);
  k_out<<<dim3(8, 64), dim3(256), 0, stream>>>(AO, Wob, bo, out);
}